// Round 9
// baseline (111.581 us; speedup 1.0000x reference)
//
#include <hip/hip_runtime.h>
#include <hip/hip_cooperative_groups.h>
#include <math.h>

namespace cg = cooperative_groups;

// Problem constants (from reference setup_inputs)
#define BB   32    // batch
#define CC   256   // channels
#define HF   64    // feature H
#define WF   64    // feature W
#define NN   256   // grid points (16x16, step 4)
#define MROWS 32   // rows per sim strip
#define NSTRIP (NN / MROWS)  // 8 strips per batch
#define SIMP 260   // padded sim row stride (floats)
#define NXCD 8
#define GBLK 256   // grid blocks (1 per CU, co-resident for grid.sync)

typedef __attribute__((ext_vector_type(8))) short    bf16x8;
typedef __attribute__((ext_vector_type(4))) float    f32x4;
typedef __attribute__((ext_vector_type(8))) unsigned short u16x8;

__device__ inline unsigned short f2bf(float f) {   // round-to-nearest-even
    unsigned u = __float_as_uint(f);
    unsigned r = u + 0x7FFFu + ((u >> 16) & 1u);
    return (unsigned short)(r >> 16);
}

// ---------------------------------------------------------------------------
// ONE cooperative kernel, 3 phases:
//  P1 gather: 2 half-blocks x (b, grid-row i) unit each; coalesced row reads,
//     LDS transpose, bf16 n-major stores + f32 norm partials + GV.
//  P2 sim: (b, 32-row strip) per block; 8 waves x 32 cols, 2(M)x2(N)
//     mfma_f32_16x16x32_bf16 tiles, 8 K-steps; scale/mask/diag; padded-LDS
//     wave-per-row softmax+argmax; per-strip partials.
//  P3 finalize: block 0 computes the two output scalars.
// XCD affinity: XCD x owns batches 4x..4x+3 in BOTH P1 and P2 (same L2).
// C/D layout (m89): col = lane&15, row = (lane>>4)*4 + reg.
// ---------------------------------------------------------------------------
__global__ __launch_bounds__(512) void fused_kernel(
        const float* __restrict__ fr,
        const float* __restrict__ fd,
        const float* __restrict__ vm,
        unsigned short* __restrict__ Dbf,
        unsigned short* __restrict__ Rbf,
        float* __restrict__ nPartD,
        float* __restrict__ nPartR,
        float* __restrict__ GV,
        float* __restrict__ lossPart,
        float* __restrict__ corrPart,
        float* __restrict__ out) {
    cg::grid_group grid = cg::this_grid();

    __shared__ float gD[2][16][257];        // 32.9 KB  (gather stage, half 0/1)
    __shared__ float gR[2][16][257];        // 32.9 KB
    __shared__ float simLds[MROWS * SIMP];  // 33.3 KB
    __shared__ float colInv[NN];
    __shared__ float validF[NN];
    __shared__ float rowInv[MROWS];
    __shared__ float diagLds[MROWS];
    __shared__ float rowLoss[MROWS];
    __shared__ float rowCorr[MROWS];
    __shared__ float sl[BB], sc2[BB], st2[BB];

    int blk = blockIdx.x;            // 256 blocks
    int t   = threadIdx.x;           // 512 threads
    int xcd = blk & (NXCD - 1);
    int q   = blk >> 3;              // 0..31 (local index within XCD)

    // ================= Phase 1: gather =================
    {
        int half = t >> 8;           // which unit this half-block handles
        int tt   = t & 255;          // channel c
        int ul   = q * 2 + half;     // 0..63 unit local to XCD
        int gb   = xcd * 4 + (ul & 3);
        int gi   = ul >> 2;          // grid row 0..15

        size_t base = ((size_t)(gb * CC + tt) * HF + 4 * gi) * WF;
#pragma unroll
        for (int j = 0; j < 16; ++j) {
            gD[half][j][tt] = fd[base + 4 * j];
            gR[half][j][tt] = fr[base + 4 * j];
        }
        __syncthreads();

        int j = tt >> 4, p = tt & 15;   // output point j, channel chunk p
        float ssd = 0.0f, ssr = 0.0f;
        unsigned short db[16], rb[16];
#pragma unroll
        for (int c2 = 0; c2 < 16; ++c2) {
            float a = gD[half][j][p * 16 + c2];
            float c = gR[half][j][p * 16 + c2];
            db[c2] = f2bf(a);
            rb[c2] = f2bf(c);
            ssd = fmaf(a, a, ssd);
            ssr = fmaf(c, c, ssr);
        }
        int n = gi * 16 + j;
        nPartD[(size_t)(gb * 16 + p) * NN + n] = ssd;
        nPartR[(size_t)(gb * 16 + p) * NN + n] = ssr;

        unsigned short* dDst = Dbf + ((size_t)(gb * NN + n) * CC + p * 16);
        unsigned short* rDst = Rbf + ((size_t)(gb * NN + n) * CC + p * 16);
        *reinterpret_cast<u16x8*>(dDst)     = *reinterpret_cast<u16x8*>(&db[0]);
        *reinterpret_cast<u16x8*>(dDst + 8) = *reinterpret_cast<u16x8*>(&db[8]);
        *reinterpret_cast<u16x8*>(rDst)     = *reinterpret_cast<u16x8*>(&rb[0]);
        *reinterpret_cast<u16x8*>(rDst + 8) = *reinterpret_cast<u16x8*>(&rb[8]);

        if (tt < 16) {
            float v = vm[((size_t)gb * 512 + 32 * gi) * 512 + 32 * tt];
            GV[(size_t)gb * NN + gi * 16 + tt] = (v > 0.5f) ? 1.0f : 0.0f;
        }
    }

    grid.sync();

    // ================= Phase 2: sim =================
    int b     = xcd * 4 + (q & 3);
    int strip = q >> 2;              // 0..7
    int nbase = strip * MROWS;

    int w  = t >> 6;                 // wave 0..7
    int l  = t & 63;
    int lg = l >> 4, lr = l & 15;

    if (t < NN) {
        float ss = 0.0f;
#pragma unroll
        for (int p = 0; p < 16; ++p) ss += nPartR[(size_t)(b * 16 + p) * NN + t];
        colInv[t] = 1.0f / fmaxf(sqrtf(ss), 1e-12f);
        validF[t] = GV[(size_t)b * NN + t];
    }
    if (t < MROWS) {
        float ss = 0.0f;
#pragma unroll
        for (int p = 0; p < 16; ++p) ss += nPartD[(size_t)(b * 16 + p) * NN + nbase + t];
        rowInv[t] = 1.0f / fmaxf(sqrtf(ss), 1e-12f);
    }
    __syncthreads();

    const unsigned short* Dp = Dbf + (size_t)(b * NN + nbase) * CC;
    const unsigned short* Rp = Rbf + (size_t)(b * NN + w * 32) * CC;

    f32x4 acc[2][2] = {};

#pragma unroll
    for (int ks = 0; ks < 8; ++ks) {
        int coff = ks * 32 + lg * 8;
        bf16x8 a0 = *reinterpret_cast<const bf16x8*>(Dp + (size_t)(lr)      * CC + coff);
        bf16x8 a1 = *reinterpret_cast<const bf16x8*>(Dp + (size_t)(16 + lr) * CC + coff);
        bf16x8 b0 = *reinterpret_cast<const bf16x8*>(Rp + (size_t)(lr)      * CC + coff);
        bf16x8 b1 = *reinterpret_cast<const bf16x8*>(Rp + (size_t)(16 + lr) * CC + coff);
        acc[0][0] = __builtin_amdgcn_mfma_f32_16x16x32_bf16(a0, b0, acc[0][0], 0, 0, 0);
        acc[0][1] = __builtin_amdgcn_mfma_f32_16x16x32_bf16(a0, b1, acc[0][1], 0, 0, 0);
        acc[1][0] = __builtin_amdgcn_mfma_f32_16x16x32_bf16(a1, b0, acc[1][0], 0, 0, 0);
        acc[1][1] = __builtin_amdgcn_mfma_f32_16x16x32_bf16(a1, b1, acc[1][1], 0, 0, 0);
    }

    const float invT = 1.0f / 0.07f;
#pragma unroll
    for (int mi = 0; mi < 2; ++mi) {
#pragma unroll
        for (int ni = 0; ni < 2; ++ni) {
            int col = w * 32 + ni * 16 + lr;
            float ci = colInv[col];
            float gv = validF[col];
#pragma unroll
            for (int reg = 0; reg < 4; ++reg) {
                int lrow = mi * 16 + lg * 4 + reg;
                float s = acc[mi][ni][reg] * invT * rowInv[lrow] * ci;
                if (col == nbase + lrow) diagLds[lrow] = s;
                simLds[lrow * SIMP + col] = (gv > 0.5f) ? s : -1e30f;
            }
        }
    }
    __syncthreads();

    // one wave per row (4 rows/wave across 8 waves)
    for (int k = w; k < MROWS; k += 8) {
        const float* row = &simLds[k * SIMP];
        float v0 = row[l];
        float v1 = row[64 + l];
        float v2 = row[128 + l];
        float v3 = row[192 + l];
        float mv = v0; int mi = l;
        if (v1 > mv) { mv = v1; mi = l + 64; }
        if (v2 > mv) { mv = v2; mi = l + 128; }
        if (v3 > mv) { mv = v3; mi = l + 192; }
#pragma unroll
        for (int off = 32; off > 0; off >>= 1) {
            float ov = __shfl_xor(mv, off, 64);
            int   oi = __shfl_xor(mi, off, 64);
            if (ov > mv || (ov == mv && oi < mi)) { mv = ov; mi = oi; }
        }
        float e = __expf(v0 - mv) + __expf(v1 - mv) + __expf(v2 - mv) + __expf(v3 - mv);
#pragma unroll
        for (int off = 32; off > 0; off >>= 1) e += __shfl_xor(e, off, 64);
        if (l == 0) {
            float vfn = validF[nbase + k];
            float lz = mv + __logf(e);
            rowLoss[k] = (vfn > 0.5f) ? (lz - diagLds[k]) : 0.0f;
            rowCorr[k] = (vfn > 0.5f && mi == nbase + k) ? 1.0f : 0.0f;
        }
    }
    __syncthreads();

    if (t == 0) {
        float la = 0.0f, ca = 0.0f;
#pragma unroll
        for (int k = 0; k < MROWS; ++k) { la += rowLoss[k]; ca += rowCorr[k]; }
        lossPart[(size_t)b * NSTRIP + strip] = la;
        corrPart[(size_t)b * NSTRIP + strip] = ca;
    }

    grid.sync();

    // ================= Phase 3: finalize (block 0) =================
    if (blk == 0) {
        int bb = t >> 3, s = t & 7;
        if (t < 256) {
            float nvp = 0.0f;
            const float4* g4 = reinterpret_cast<const float4*>(GV + (size_t)bb * NN);
#pragma unroll
            for (int qq = 0; qq < 8; ++qq) {
                float4 v = g4[s * 8 + qq];
                nvp += v.x + v.y + v.z + v.w;
            }
#pragma unroll
            for (int off = 1; off < 8; off <<= 1) nvp += __shfl_xor(nvp, off, 64);

            if (s == 0) {
                float lb = 0.0f, cb = 0.0f;
#pragma unroll
                for (int k = 0; k < NSTRIP; ++k) {
                    lb += lossPart[bb * NSTRIP + k];
                    cb += corrPart[bb * NSTRIP + k];
                }
                bool inc = (nvp >= 2.0f);
                sl[bb]  = inc ? (lb / fmaxf(nvp, 1.0f)) : 0.0f;
                sc2[bb] = inc ? cb : 0.0f;
                st2[bb] = inc ? nvp : 0.0f;
            }
        }
        __syncthreads();
        if (t == 0) {
            float L = 0.0f, Ccnt = 0.0f, Tcnt = 0.0f;
            for (int qq = 0; qq < BB; ++qq) { L += sl[qq]; Ccnt += sc2[qq]; Tcnt += st2[qq]; }
            float avg = L / (float)BB;
            out[0] = (Tcnt > 0.0f) ? avg : 0.0f;
            out[1] = (Tcnt > 0.0f) ? (Ccnt / fmaxf(Tcnt, 1.0f) * 100.0f) : 0.0f;
        }
    }
}

extern "C" void kernel_launch(void* const* d_in, const int* in_sizes, int n_in,
                              void* d_out, int out_size, void* d_ws, size_t ws_size,
                              hipStream_t stream) {
    const float* fr = (const float*)d_in[0];  // fmap_rgb
    const float* fd = (const float*)d_in[1];  // fmap_depth
    // d_in[2] = projected_coords: DEAD in reference (_rgb_pos never used)
    const float* vm = (const float*)d_in[3];  // valid_mask

    float* outp = (float*)d_out;
    char* ws = (char*)d_ws;

    // Workspace layout (~9.1 MB total)
    size_t featBytes = (size_t)BB * NN * CC * 2;        // 4 MB each (bf16)
    size_t partBytes = (size_t)BB * 16 * NN * 4;        // 512 KB each
    unsigned short* Dbf = (unsigned short*)ws;
    unsigned short* Rbf = (unsigned short*)(ws + featBytes);
    float* nPartD   = (float*)(ws + 2 * featBytes);
    float* nPartR   = (float*)(ws + 2 * featBytes + partBytes);
    float* GV       = (float*)(ws + 2 * featBytes + 2 * partBytes);
    float* lossPart = GV + (size_t)BB * NN;             // BB*NSTRIP
    float* corrPart = lossPart + BB * NSTRIP;           // BB*NSTRIP

    void* args[] = {
        (void*)&fr, (void*)&fd, (void*)&vm,
        (void*)&Dbf, (void*)&Rbf, (void*)&nPartD, (void*)&nPartR,
        (void*)&GV, (void*)&lossPart, (void*)&corrPart, (void*)&outp
    };
    hipLaunchCooperativeKernel((void*)fused_kernel, dim3(GBLK), dim3(512),
                               args, 0, stream);
}

// Round 10
// 51.133 us; speedup vs baseline: 2.1822x; 2.1822x over previous
//
#include <hip/hip_runtime.h>
#include <math.h>

// Problem constants (from reference setup_inputs)
#define BB   32    // batch
#define CC   256   // channels
#define HF   64    // feature H
#define WF   64    // feature W
#define NN   256   // grid points (16x16, step 4)
#define MROWS 32   // rows per sim strip
#define NSTRIP (NN / MROWS)  // 8 strips per batch
#define SIMP 260   // padded sim row stride (floats)
#define NXCD 8
#define SIMBLOCKS (BB * NSTRIP)   // 256

typedef __attribute__((ext_vector_type(8))) short    bf16x8;
typedef __attribute__((ext_vector_type(4))) float    f32x4;
typedef __attribute__((ext_vector_type(8))) unsigned short u16x8;

__device__ inline unsigned short f2bf(float f) {   // round-to-nearest-even
    unsigned u = __float_as_uint(f);
    unsigned r = u + 0x7FFFu + ((u >> 16) & 1u);
    return (unsigned short)(r >> 16);
}

// ---------------------------------------------------------------------------
// Kernel A: block = (b, grid-row i). Lane = channel c. Coalesced-ish row
// reads (4 lines/channel-row, L1 absorbs x4 reuse), LDS transpose, fully
// coalesced bf16 n-major stores + f32 norm partials + GV.
// Block 0 thread 0 also zero-inits doneCnt for kernel B's last-block logic
// (kernel-boundary ordering makes this safe; removes a memset dispatch).
// XCD-swizzled to match sim (XCD x owns batches 4x..4x+3).
// ---------------------------------------------------------------------------
__global__ __launch_bounds__(256) void gather_kernel(
        const float* __restrict__ fr,
        const float* __restrict__ fd,
        const float* __restrict__ vm,
        unsigned short* __restrict__ Dbf,
        unsigned short* __restrict__ Rbf,
        float* __restrict__ nPartD,
        float* __restrict__ nPartR,
        float* __restrict__ GV,
        unsigned int* __restrict__ doneCnt) {
    __shared__ float ldsD[16][257];   // [j][c], +1 pad
    __shared__ float ldsR[16][257];

    int blk = blockIdx.x;             // 512 blocks
    int xcd = blk & (NXCD - 1);
    int r   = blk >> 3;
    int b   = xcd * 4 + (r & 3);
    int i   = r >> 2;                 // grid row 0..15
    int t   = threadIdx.x;            // channel c

    if (blk == 0 && t == 0) *doneCnt = 0u;

    size_t base = ((size_t)(b * CC + t) * HF + 4 * i) * WF;
#pragma unroll
    for (int j = 0; j < 16; ++j) {
        ldsD[j][t] = fd[base + 4 * j];
        ldsR[j][t] = fr[base + 4 * j];
    }
    __syncthreads();

    int j = t >> 4, p = t & 15;       // output point j, channel chunk p
    float ssd = 0.0f, ssr = 0.0f;
    unsigned short db[16], rb[16];
#pragma unroll
    for (int q = 0; q < 16; ++q) {
        float a  = ldsD[j][p * 16 + q];
        float c2 = ldsR[j][p * 16 + q];
        db[q] = f2bf(a);
        rb[q] = f2bf(c2);
        ssd = fmaf(a, a, ssd);
        ssr = fmaf(c2, c2, ssr);
    }
    int n = i * 16 + j;
    nPartD[(size_t)(b * 16 + p) * NN + n] = ssd;
    nPartR[(size_t)(b * 16 + p) * NN + n] = ssr;

    unsigned short* dDst = Dbf + ((size_t)(b * NN + n) * CC + p * 16);
    unsigned short* rDst = Rbf + ((size_t)(b * NN + n) * CC + p * 16);
    *reinterpret_cast<u16x8*>(dDst)     = *reinterpret_cast<u16x8*>(&db[0]);
    *reinterpret_cast<u16x8*>(dDst + 8) = *reinterpret_cast<u16x8*>(&db[8]);
    *reinterpret_cast<u16x8*>(rDst)     = *reinterpret_cast<u16x8*>(&rb[0]);
    *reinterpret_cast<u16x8*>(rDst + 8) = *reinterpret_cast<u16x8*>(&rb[8]);

    if (t < 16) {
        float v = vm[((size_t)b * 512 + 32 * i) * 512 + 32 * t];
        GV[(size_t)b * NN + i * 16 + t] = (v > 0.5f) ? 1.0f : 0.0f;
    }
}

// ---------------------------------------------------------------------------
// Kernel B: MFMA sim (R6-verbatim GEMM+softmax, the 38.7 us structure)
// + fused finalize via last-block-done.
// Block = (b, 32-row strip), 256 blocks, 4 waves. Wave w: rows [nbase,+32) x
// cols [w*64,+64) via 2(M)x4(N) mfma_f32_16x16x32_bf16, 8 K-steps.
// C/D layout (m89): col = lane&15, row = (lane>>4)*4 + reg.
// ---------------------------------------------------------------------------
__global__ __launch_bounds__(256) void sim_loss_kernel(
        const unsigned short* __restrict__ Dbf,
        const unsigned short* __restrict__ Rbf,
        const float* __restrict__ nPartD,
        const float* __restrict__ nPartR,
        const float* __restrict__ GV,
        float* __restrict__ lossPart,
        float* __restrict__ corrPart,
        unsigned int* __restrict__ doneCnt,
        float* __restrict__ out) {
    __shared__ float simLds[MROWS * SIMP];   // 33.3 KB
    __shared__ float colInv[NN];
    __shared__ float validF[NN];
    __shared__ float rowInv[MROWS];
    __shared__ float diagLds[MROWS];
    __shared__ float rowLoss[MROWS];
    __shared__ float rowCorr[MROWS];
    __shared__ int   lastFlag;

    int blk   = blockIdx.x;                  // 256 blocks
    int xcd   = blk & (NXCD - 1);
    int rr    = blk >> 3;
    int b     = xcd * 4 + (rr & 3);
    int strip = rr >> 2;
    int nbase = strip * MROWS;

    int t  = threadIdx.x;
    int w  = t >> 6;
    int l  = t & 63;
    int lg = l >> 4, lr = l & 15;

    // ---- norms + validity into LDS ----
    {
        float ss = 0.0f;
#pragma unroll
        for (int p = 0; p < 16; ++p) ss += nPartR[(size_t)(b * 16 + p) * NN + t];
        colInv[t] = 1.0f / fmaxf(sqrtf(ss), 1e-12f);
        validF[t] = GV[(size_t)b * NN + t];
    }
    if (t < MROWS) {
        float ss = 0.0f;
#pragma unroll
        for (int p = 0; p < 16; ++p) ss += nPartD[(size_t)(b * 16 + p) * NN + nbase + t];
        rowInv[t] = 1.0f / fmaxf(sqrtf(ss), 1e-12f);
    }
    __syncthreads();

    // ---- MFMA GEMM ----
    const unsigned short* Dp = Dbf + (size_t)(b * NN + nbase) * CC;
    const unsigned short* Rp = Rbf + (size_t)b * NN * CC;

    f32x4 acc[2][4] = {};

#pragma unroll
    for (int ks = 0; ks < 8; ++ks) {
        int coff = ks * 32 + lg * 8;
        bf16x8 a0 = *reinterpret_cast<const bf16x8*>(Dp + (size_t)(lr)      * CC + coff);
        bf16x8 a1 = *reinterpret_cast<const bf16x8*>(Dp + (size_t)(16 + lr) * CC + coff);
        bf16x8 b0 = *reinterpret_cast<const bf16x8*>(Rp + (size_t)(w * 64 +  0 + lr) * CC + coff);
        bf16x8 b1 = *reinterpret_cast<const bf16x8*>(Rp + (size_t)(w * 64 + 16 + lr) * CC + coff);
        bf16x8 b2 = *reinterpret_cast<const bf16x8*>(Rp + (size_t)(w * 64 + 32 + lr) * CC + coff);
        bf16x8 b3 = *reinterpret_cast<const bf16x8*>(Rp + (size_t)(w * 64 + 48 + lr) * CC + coff);
        acc[0][0] = __builtin_amdgcn_mfma_f32_16x16x32_bf16(a0, b0, acc[0][0], 0, 0, 0);
        acc[0][1] = __builtin_amdgcn_mfma_f32_16x16x32_bf16(a0, b1, acc[0][1], 0, 0, 0);
        acc[0][2] = __builtin_amdgcn_mfma_f32_16x16x32_bf16(a0, b2, acc[0][2], 0, 0, 0);
        acc[0][3] = __builtin_amdgcn_mfma_f32_16x16x32_bf16(a0, b3, acc[0][3], 0, 0, 0);
        acc[1][0] = __builtin_amdgcn_mfma_f32_16x16x32_bf16(a1, b0, acc[1][0], 0, 0, 0);
        acc[1][1] = __builtin_amdgcn_mfma_f32_16x16x32_bf16(a1, b1, acc[1][1], 0, 0, 0);
        acc[1][2] = __builtin_amdgcn_mfma_f32_16x16x32_bf16(a1, b2, acc[1][2], 0, 0, 0);
        acc[1][3] = __builtin_amdgcn_mfma_f32_16x16x32_bf16(a1, b3, acc[1][3], 0, 0, 0);
    }

    // ---- epilogue: scale, diag capture, mask, store rows to LDS ----
    const float invT = 1.0f / 0.07f;
#pragma unroll
    for (int mi = 0; mi < 2; ++mi) {
#pragma unroll
        for (int ni = 0; ni < 4; ++ni) {
            int col = w * 64 + ni * 16 + lr;
            float ci = colInv[col];
            float gv = validF[col];
#pragma unroll
            for (int reg = 0; reg < 4; ++reg) {
                int lrow = mi * 16 + lg * 4 + reg;
                float s = acc[mi][ni][reg] * invT * rowInv[lrow] * ci;
                if (col == nbase + lrow) diagLds[lrow] = s;
                simLds[lrow * SIMP + col] = (gv > 0.5f) ? s : -1e30f;
            }
        }
    }
    __syncthreads();

    // ---- one wave per row: max/argmax + sum-exp via shfl only ----
    for (int k = w; k < MROWS; k += 4) {
        const float* row = &simLds[k * SIMP];
        float v0 = row[l];
        float v1 = row[64 + l];
        float v2 = row[128 + l];
        float v3 = row[192 + l];
        float mv = v0; int mi = l;
        if (v1 > mv) { mv = v1; mi = l + 64; }
        if (v2 > mv) { mv = v2; mi = l + 128; }
        if (v3 > mv) { mv = v3; mi = l + 192; }
#pragma unroll
        for (int off = 32; off > 0; off >>= 1) {
            float ov = __shfl_xor(mv, off, 64);
            int   oi = __shfl_xor(mi, off, 64);
            if (ov > mv || (ov == mv && oi < mi)) { mv = ov; mi = oi; }
        }
        float e = __expf(v0 - mv) + __expf(v1 - mv) + __expf(v2 - mv) + __expf(v3 - mv);
#pragma unroll
        for (int off = 32; off > 0; off >>= 1) e += __shfl_xor(e, off, 64);
        if (l == 0) {
            float vfn = validF[nbase + k];
            float lz = mv + __logf(e);
            rowLoss[k] = (vfn > 0.5f) ? (lz - diagLds[k]) : 0.0f;
            rowCorr[k] = (vfn > 0.5f && mi == nbase + k) ? 1.0f : 0.0f;
        }
    }
    __syncthreads();

    if (t == 0) {
        float la = 0.0f, ca = 0.0f;
#pragma unroll
        for (int k = 0; k < MROWS; ++k) { la += rowLoss[k]; ca += rowCorr[k]; }
        lossPart[(size_t)b * NSTRIP + strip] = la;
        corrPart[(size_t)b * NSTRIP + strip] = ca;
        __threadfence();                              // partials visible device-wide
        unsigned old = atomicAdd(doneCnt, 1u);        // device-scope
        lastFlag = (old == SIMBLOCKS - 1) ? 1 : 0;
    }
    __syncthreads();

    // ---- fused finalize: only the last block runs this ----
    if (lastFlag) {
        __threadfence();   // acquire: see all other blocks' partials
        __shared__ float sl[BB], sc2[BB], st2[BB];
        int bb = t >> 3, s = t & 7;

        float nvp = 0.0f;
        const float4* g4 = reinterpret_cast<const float4*>(GV + (size_t)bb * NN);
#pragma unroll
        for (int q = 0; q < 8; ++q) {
            float4 v = g4[s * 8 + q];
            nvp += v.x + v.y + v.z + v.w;
        }
#pragma unroll
        for (int off = 1; off < 8; off <<= 1) nvp += __shfl_xor(nvp, off, 64);

        if (s == 0) {
            float lb = 0.0f, cb = 0.0f;
#pragma unroll
            for (int k = 0; k < NSTRIP; ++k) {
                lb += lossPart[bb * NSTRIP + k];
                cb += corrPart[bb * NSTRIP + k];
            }
            bool inc = (nvp >= 2.0f);
            sl[bb]  = inc ? (lb / fmaxf(nvp, 1.0f)) : 0.0f;
            sc2[bb] = inc ? cb : 0.0f;
            st2[bb] = inc ? nvp : 0.0f;
        }
        __syncthreads();
        if (t == 0) {
            float L = 0.0f, Ccnt = 0.0f, Tcnt = 0.0f;
            for (int q = 0; q < BB; ++q) { L += sl[q]; Ccnt += sc2[q]; Tcnt += st2[q]; }
            float avg = L / (float)BB;
            out[0] = (Tcnt > 0.0f) ? avg : 0.0f;
            out[1] = (Tcnt > 0.0f) ? (Ccnt / fmaxf(Tcnt, 1.0f) * 100.0f) : 0.0f;
        }
    }
}

extern "C" void kernel_launch(void* const* d_in, const int* in_sizes, int n_in,
                              void* d_out, int out_size, void* d_ws, size_t ws_size,
                              hipStream_t stream) {
    const float* fr = (const float*)d_in[0];  // fmap_rgb
    const float* fd = (const float*)d_in[1];  // fmap_depth
    // d_in[2] = projected_coords: DEAD in reference (_rgb_pos never used)
    const float* vm = (const float*)d_in[3];  // valid_mask

    float* out = (float*)d_out;
    char* ws = (char*)d_ws;

    // Workspace layout (~9.1 MB total)
    size_t featBytes = (size_t)BB * NN * CC * 2;        // 4 MB each (bf16)
    size_t partBytes = (size_t)BB * 16 * NN * 4;        // 512 KB each
    unsigned short* Dbf = (unsigned short*)ws;
    unsigned short* Rbf = (unsigned short*)(ws + featBytes);
    float* nPartD   = (float*)(ws + 2 * featBytes);
    float* nPartR   = (float*)(ws + 2 * featBytes + partBytes);
    float* GV       = (float*)(ws + 2 * featBytes + 2 * partBytes);
    float* lossPart = GV + (size_t)BB * NN;             // BB*NSTRIP
    float* corrPart = lossPart + BB * NSTRIP;           // BB*NSTRIP
    unsigned int* doneCnt = (unsigned int*)(corrPart + BB * NSTRIP);

    hipLaunchKernelGGL(gather_kernel, dim3(BB * 16), dim3(256), 0, stream,
                       fr, fd, vm, Dbf, Rbf, nPartD, nPartR, GV, doneCnt);
    hipLaunchKernelGGL(sim_loss_kernel, dim3(SIMBLOCKS), dim3(256), 0, stream,
                       Dbf, Rbf, nPartD, nPartR, GV, lossPart, corrPart,
                       doneCnt, out);
}

// Round 11
// 39.854 us; speedup vs baseline: 2.7998x; 1.2830x over previous
//
#include <hip/hip_runtime.h>
#include <math.h>

// Problem constants (from reference setup_inputs)
#define BB   32    // batch
#define CC   256   // channels
#define HF   64    // feature H
#define WF   64    // feature W
#define NN   256   // grid points (16x16, step 4)
#define MROWS 32   // rows per sim strip
#define NSTRIP (NN / MROWS)  // 8 strips per batch
#define SIMP 260   // padded sim row stride (floats)
#define NXCD 8

typedef __attribute__((ext_vector_type(8))) short    bf16x8;
typedef __attribute__((ext_vector_type(4))) float    f32x4;
typedef __attribute__((ext_vector_type(8))) unsigned short u16x8;

__device__ inline unsigned short f2bf(float f) {   // round-to-nearest-even
    unsigned u = __float_as_uint(f);
    unsigned r = u + 0x7FFFu + ((u >> 16) & 1u);
    return (unsigned short)(r >> 16);
}

// ---------------------------------------------------------------------------
// Kernel A: block = (b, grid-row i).
// LOAD PHASE (new): lane (g=t>>4, k=t&15); for it=0..15, channel c=it*16+g,
// lane loads float4 #k of fmap row y=4i (16B coalesced within each 16-lane
// group -> 16 line-touches/instr instead of 64) and keeps .x = point x=4k.
// TRANSPOSE/STORE PHASE (R8-exact): thread (j=t>>4, p=t&15) computes f32
// sumsq partial for its 16 channels, writes coalesced 32B bf16 chunks.
//   Dbf/Rbf[b][n][c] (bf16), nPartD/nPartR[b][p][n] (f32), GV[b][n]
// XCD-swizzled to match sim (XCD x owns batches 4x..4x+3).
// ---------------------------------------------------------------------------
__global__ __launch_bounds__(256) void gather_kernel(
        const float* __restrict__ fr,
        const float* __restrict__ fd,
        const float* __restrict__ vm,
        unsigned short* __restrict__ Dbf,
        unsigned short* __restrict__ Rbf,
        float* __restrict__ nPartD,
        float* __restrict__ nPartR,
        float* __restrict__ GV) {
    __shared__ float ldsD[16][257];   // [j][c], +1 pad
    __shared__ float ldsR[16][257];

    int blk = blockIdx.x;             // 512 blocks
    int xcd = blk & (NXCD - 1);
    int r   = blk >> 3;
    int b   = xcd * 4 + (r & 3);
    int i   = r >> 2;                 // grid row 0..15
    int t   = threadIdx.x;
    int g   = t >> 4;                 // row-unit subgroup 0..15
    int k   = t & 15;                 // point index j / float4 slot

    // depth map: 16 iterations, channel c = it*16 + g
#pragma unroll
    for (int it = 0; it < 16; ++it) {
        int c = it * 16 + g;
        const float4* row = reinterpret_cast<const float4*>(
            fd + ((size_t)(b * CC + c) * HF + 4 * i) * WF);
        float4 v = row[k];            // coalesced 16B; .x = point x=4k
        ldsD[k][c] = v.x;
    }
    // rgb map
#pragma unroll
    for (int it = 0; it < 16; ++it) {
        int c = it * 16 + g;
        const float4* row = reinterpret_cast<const float4*>(
            fr + ((size_t)(b * CC + c) * HF + 4 * i) * WF);
        float4 v = row[k];
        ldsR[k][c] = v.x;
    }
    __syncthreads();

    int j = t >> 4, p = t & 15;       // output point j, channel chunk p
    float ssd = 0.0f, ssr = 0.0f;
    unsigned short db[16], rb[16];
#pragma unroll
    for (int q = 0; q < 16; ++q) {
        float a  = ldsD[j][p * 16 + q];
        float c2 = ldsR[j][p * 16 + q];
        db[q] = f2bf(a);
        rb[q] = f2bf(c2);
        ssd = fmaf(a, a, ssd);
        ssr = fmaf(c2, c2, ssr);
    }
    int n = i * 16 + j;
    nPartD[(size_t)(b * 16 + p) * NN + n] = ssd;
    nPartR[(size_t)(b * 16 + p) * NN + n] = ssr;

    unsigned short* dDst = Dbf + ((size_t)(b * NN + n) * CC + p * 16);
    unsigned short* rDst = Rbf + ((size_t)(b * NN + n) * CC + p * 16);
    *reinterpret_cast<u16x8*>(dDst)     = *reinterpret_cast<u16x8*>(&db[0]);
    *reinterpret_cast<u16x8*>(dDst + 8) = *reinterpret_cast<u16x8*>(&db[8]);
    *reinterpret_cast<u16x8*>(rDst)     = *reinterpret_cast<u16x8*>(&rb[0]);
    *reinterpret_cast<u16x8*>(rDst + 8) = *reinterpret_cast<u16x8*>(&rb[8]);

    if (t < 16) {
        float v = vm[((size_t)b * 512 + 32 * i) * 512 + 32 * t];
        GV[(size_t)b * NN + i * 16 + t] = (v > 0.5f) ? 1.0f : 0.0f;
    }
}

// ---------------------------------------------------------------------------
// Kernel B: MFMA sim (R6-verbatim, the 38.7 us structure).
// Block = (b, 32-row strip), 256 blocks, 4 waves. Wave w: rows [nbase,+32) x
// cols [w*64,+64) via 2(M)x4(N) mfma_f32_16x16x32_bf16, 8 K-steps.
// C/D layout (m89): col = lane&15, row = (lane>>4)*4 + reg.
// ---------------------------------------------------------------------------
__global__ __launch_bounds__(256) void sim_loss_kernel(
        const unsigned short* __restrict__ Dbf,
        const unsigned short* __restrict__ Rbf,
        const float* __restrict__ nPartD,
        const float* __restrict__ nPartR,
        const float* __restrict__ GV,
        float* __restrict__ lossPart,
        float* __restrict__ corrPart) {
    __shared__ float simLds[MROWS * SIMP];   // 33.3 KB
    __shared__ float colInv[NN];
    __shared__ float validF[NN];
    __shared__ float rowInv[MROWS];
    __shared__ float diagLds[MROWS];
    __shared__ float rowLoss[MROWS];
    __shared__ float rowCorr[MROWS];

    int blk   = blockIdx.x;                  // 256 blocks
    int xcd   = blk & (NXCD - 1);
    int rr    = blk >> 3;
    int b     = xcd * 4 + (rr & 3);
    int strip = rr >> 2;
    int nbase = strip * MROWS;

    int t  = threadIdx.x;
    int w  = t >> 6;
    int l  = t & 63;
    int lg = l >> 4, lr = l & 15;

    // ---- norms + validity into LDS ----
    {
        float ss = 0.0f;
#pragma unroll
        for (int p = 0; p < 16; ++p) ss += nPartR[(size_t)(b * 16 + p) * NN + t];
        colInv[t] = 1.0f / fmaxf(sqrtf(ss), 1e-12f);
        validF[t] = GV[(size_t)b * NN + t];
    }
    if (t < MROWS) {
        float ss = 0.0f;
#pragma unroll
        for (int p = 0; p < 16; ++p) ss += nPartD[(size_t)(b * 16 + p) * NN + nbase + t];
        rowInv[t] = 1.0f / fmaxf(sqrtf(ss), 1e-12f);
    }
    __syncthreads();

    // ---- MFMA GEMM ----
    const unsigned short* Dp = Dbf + (size_t)(b * NN + nbase) * CC;
    const unsigned short* Rp = Rbf + (size_t)b * NN * CC;

    f32x4 acc[2][4] = {};

#pragma unroll
    for (int ks = 0; ks < 8; ++ks) {
        int coff = ks * 32 + lg * 8;
        bf16x8 a0 = *reinterpret_cast<const bf16x8*>(Dp + (size_t)(lr)      * CC + coff);
        bf16x8 a1 = *reinterpret_cast<const bf16x8*>(Dp + (size_t)(16 + lr) * CC + coff);
        bf16x8 b0 = *reinterpret_cast<const bf16x8*>(Rp + (size_t)(w * 64 +  0 + lr) * CC + coff);
        bf16x8 b1 = *reinterpret_cast<const bf16x8*>(Rp + (size_t)(w * 64 + 16 + lr) * CC + coff);
        bf16x8 b2 = *reinterpret_cast<const bf16x8*>(Rp + (size_t)(w * 64 + 32 + lr) * CC + coff);
        bf16x8 b3 = *reinterpret_cast<const bf16x8*>(Rp + (size_t)(w * 64 + 48 + lr) * CC + coff);
        acc[0][0] = __builtin_amdgcn_mfma_f32_16x16x32_bf16(a0, b0, acc[0][0], 0, 0, 0);
        acc[0][1] = __builtin_amdgcn_mfma_f32_16x16x32_bf16(a0, b1, acc[0][1], 0, 0, 0);
        acc[0][2] = __builtin_amdgcn_mfma_f32_16x16x32_bf16(a0, b2, acc[0][2], 0, 0, 0);
        acc[0][3] = __builtin_amdgcn_mfma_f32_16x16x32_bf16(a0, b3, acc[0][3], 0, 0, 0);
        acc[1][0] = __builtin_amdgcn_mfma_f32_16x16x32_bf16(a1, b0, acc[1][0], 0, 0, 0);
        acc[1][1] = __builtin_amdgcn_mfma_f32_16x16x32_bf16(a1, b1, acc[1][1], 0, 0, 0);
        acc[1][2] = __builtin_amdgcn_mfma_f32_16x16x32_bf16(a1, b2, acc[1][2], 0, 0, 0);
        acc[1][3] = __builtin_amdgcn_mfma_f32_16x16x32_bf16(a1, b3, acc[1][3], 0, 0, 0);
    }

    // ---- epilogue: scale, diag capture, mask, store rows to LDS ----
    const float invT = 1.0f / 0.07f;
#pragma unroll
    for (int mi = 0; mi < 2; ++mi) {
#pragma unroll
        for (int ni = 0; ni < 4; ++ni) {
            int col = w * 64 + ni * 16 + lr;
            float ci = colInv[col];
            float gv = validF[col];
#pragma unroll
            for (int reg = 0; reg < 4; ++reg) {
                int lrow = mi * 16 + lg * 4 + reg;
                float s = acc[mi][ni][reg] * invT * rowInv[lrow] * ci;
                if (col == nbase + lrow) diagLds[lrow] = s;
                simLds[lrow * SIMP + col] = (gv > 0.5f) ? s : -1e30f;
            }
        }
    }
    __syncthreads();

    // ---- one wave per row: max/argmax + sum-exp via shfl only ----
    for (int k = w; k < MROWS; k += 4) {
        const float* row = &simLds[k * SIMP];
        float v0 = row[l];
        float v1 = row[64 + l];
        float v2 = row[128 + l];
        float v3 = row[192 + l];
        float mv = v0; int mi = l;
        if (v1 > mv) { mv = v1; mi = l + 64; }
        if (v2 > mv) { mv = v2; mi = l + 128; }
        if (v3 > mv) { mv = v3; mi = l + 192; }
#pragma unroll
        for (int off = 32; off > 0; off >>= 1) {
            float ov = __shfl_xor(mv, off, 64);
            int   oi = __shfl_xor(mi, off, 64);
            if (ov > mv || (ov == mv && oi < mi)) { mv = ov; mi = oi; }
        }
        float e = __expf(v0 - mv) + __expf(v1 - mv) + __expf(v2 - mv) + __expf(v3 - mv);
#pragma unroll
        for (int off = 32; off > 0; off >>= 1) e += __shfl_xor(e, off, 64);
        if (l == 0) {
            float vfn = validF[nbase + k];
            float lz = mv + __logf(e);
            rowLoss[k] = (vfn > 0.5f) ? (lz - diagLds[k]) : 0.0f;
            rowCorr[k] = (vfn > 0.5f && mi == nbase + k) ? 1.0f : 0.0f;
        }
    }
    __syncthreads();

    if (t == 0) {
        float la = 0.0f, ca = 0.0f;
#pragma unroll
        for (int k = 0; k < MROWS; ++k) { la += rowLoss[k]; ca += rowCorr[k]; }
        lossPart[(size_t)b * NSTRIP + strip] = la;
        corrPart[(size_t)b * NSTRIP + strip] = ca;
    }
}

// ---------------------------------------------------------------------------
// Kernel C: per-batch include / n_valid logic, final two scalars.
// ---------------------------------------------------------------------------
__global__ __launch_bounds__(256) void finalize_kernel(
        const float* __restrict__ GV,
        const float* __restrict__ lossPart,
        const float* __restrict__ corrPart,
        float* __restrict__ out) {
    __shared__ float sl[BB], sc2[BB], st2[BB];
    int t = threadIdx.x;           // 256 threads: 8 per batch
    int b = t >> 3, s = t & 7;

    float nvp = 0.0f;
    const float4* g4 = reinterpret_cast<const float4*>(GV + (size_t)b * NN);
#pragma unroll
    for (int q = 0; q < 8; ++q) {
        float4 v = g4[s * 8 + q];
        nvp += v.x + v.y + v.z + v.w;
    }
#pragma unroll
    for (int off = 1; off < 8; off <<= 1) nvp += __shfl_xor(nvp, off, 64);

    if (s == 0) {
        float lb = 0.0f, cb = 0.0f;
#pragma unroll
        for (int k = 0; k < NSTRIP; ++k) {
            lb += lossPart[b * NSTRIP + k];
            cb += corrPart[b * NSTRIP + k];
        }
        bool inc = (nvp >= 2.0f);
        sl[b]  = inc ? (lb / fmaxf(nvp, 1.0f)) : 0.0f;
        sc2[b] = inc ? cb : 0.0f;
        st2[b] = inc ? nvp : 0.0f;
    }
    __syncthreads();
    if (t == 0) {
        float L = 0.0f, Ccnt = 0.0f, Tcnt = 0.0f;
        for (int bb = 0; bb < BB; ++bb) { L += sl[bb]; Ccnt += sc2[bb]; Tcnt += st2[bb]; }
        float avg = L / (float)BB;
        out[0] = (Tcnt > 0.0f) ? avg : 0.0f;
        out[1] = (Tcnt > 0.0f) ? (Ccnt / fmaxf(Tcnt, 1.0f) * 100.0f) : 0.0f;
    }
}

extern "C" void kernel_launch(void* const* d_in, const int* in_sizes, int n_in,
                              void* d_out, int out_size, void* d_ws, size_t ws_size,
                              hipStream_t stream) {
    const float* fr = (const float*)d_in[0];  // fmap_rgb
    const float* fd = (const float*)d_in[1];  // fmap_depth
    // d_in[2] = projected_coords: DEAD in reference (_rgb_pos never used)
    const float* vm = (const float*)d_in[3];  // valid_mask

    float* out = (float*)d_out;
    char* ws = (char*)d_ws;

    // Workspace layout (~9.1 MB total)
    size_t featBytes = (size_t)BB * NN * CC * 2;        // 4 MB each (bf16)
    size_t partBytes = (size_t)BB * 16 * NN * 4;        // 512 KB each
    unsigned short* Dbf = (unsigned short*)ws;
    unsigned short* Rbf = (unsigned short*)(ws + featBytes);
    float* nPartD   = (float*)(ws + 2 * featBytes);
    float* nPartR   = (float*)(ws + 2 * featBytes + partBytes);
    float* GV       = (float*)(ws + 2 * featBytes + 2 * partBytes);
    float* lossPart = GV + (size_t)BB * NN;             // BB*NSTRIP
    float* corrPart = lossPart + BB * NSTRIP;           // BB*NSTRIP

    hipLaunchKernelGGL(gather_kernel, dim3(BB * 16), dim3(256), 0, stream,
                       fr, fd, vm, Dbf, Rbf, nPartD, nPartR, GV);
    hipLaunchKernelGGL(sim_loss_kernel, dim3(BB * NSTRIP), dim3(256), 0, stream,
                       Dbf, Rbf, nPartD, nPartR, GV, lossPart, corrPart);
    hipLaunchKernelGGL(finalize_kernel, dim3(1), dim3(256), 0, stream,
                       GV, lossPart, corrPart, out);
}